// Round 7
// baseline (307.908 us; speedup 1.0000x reference)
//
#include <hip/hip_runtime.h>
#include <hip/hip_bf16.h>

// Problem: B=4, T=2048, C=1024, H=16, HS=64. M = B*T = 8192.
#define B_ 4
#define T_ 2048
#define C_ 1024
#define H_ 16
#define HS_ 64
#define M_ (B_*T_)
#define QSCALE 0.18033688011112042f   // 0.125 * log2(e): softmax in exp2 domain

typedef __bf16 bf16_t;
typedef bf16_t bf16x8 __attribute__((ext_vector_type(8)));
typedef float f32x4 __attribute__((ext_vector_type(4)));
typedef unsigned short ushort_t;

__device__ __forceinline__ unsigned short f2bf(float f) {
    __hip_bfloat16 h = __float2bfloat16(f);
    return __builtin_bit_cast(unsigned short, h);
}

__device__ __forceinline__ void glds16(const void* g, void* l) {
    __builtin_amdgcn_global_load_lds((const __attribute__((address_space(1))) void*)g,
                                     (__attribute__((address_space(3))) void*)l, 16, 0, 0);
}

// ---------------- prep: x fp32 -> bf16 row-major ----------------
__launch_bounds__(256)
__global__ void cvt_x(const float* __restrict__ in, ushort_t* __restrict__ out) {
    int i = blockIdx.x * 256 + threadIdx.x;   // 8 elems per thread
    const float4* p = (const float4*)in;
    float4 a = p[i * 2], b = p[i * 2 + 1];
    ushort4 o0, o1;
    o0.x = f2bf(a.x); o0.y = f2bf(a.y); o0.z = f2bf(a.z); o0.w = f2bf(a.w);
    o1.x = f2bf(b.x); o1.y = f2bf(b.y); o1.z = f2bf(b.z); o1.w = f2bf(b.w);
    *(ushort4*)&out[i * 8] = o0;
    *(ushort4*)&out[i * 8 + 4] = o1;
}

// ---------------- prep: w [K][N] fp32 -> wT [N][K] bf16 (64x64 LDS tiles) ----------------
__launch_bounds__(256)
__global__ void transpose_cvt(const float* __restrict__ w, ushort_t* __restrict__ wT,
                              int K, int N) {
    __shared__ ushort_t Ts[64][72];
    const int n0 = blockIdx.x * 64, k0 = blockIdx.y * 64;
    const int t = threadIdx.x, r = t >> 2, cq = t & 3;
    #pragma unroll
    for (int j = 0; j < 4; j++) {
        float4 v = *(const float4*)&w[(size_t)(k0 + r) * N + n0 + cq * 16 + j * 4];
        ushort4 o;
        o.x = f2bf(v.x); o.y = f2bf(v.y); o.z = f2bf(v.z); o.w = f2bf(v.w);
        *(ushort4*)&Ts[r][cq * 16 + j * 4] = o;
    }
    __syncthreads();
    #pragma unroll
    for (int j = 0; j < 4; j++) {
        ushort4 o;
        o.x = Ts[cq * 16 + j * 4 + 0][r];
        o.y = Ts[cq * 16 + j * 4 + 1][r];
        o.z = Ts[cq * 16 + j * 4 + 2][r];
        o.w = Ts[cq * 16 + j * 4 + 3][r];
        *(ushort4*)&wT[(size_t)(n0 + r) * K + k0 + cq * 16 + j * 4] = o;
    }
}

// ---------------- QKV GEMM: BK=64, 128x128 tile, glds16 staging ----------------
// Q -> [B,H,T,HS] PRESCALED by QSCALE; K -> [B,H,T,HS]; V -> transposed [B,H,HS,T].
__launch_bounds__(256)
__global__ void qkv_gemm(const ushort_t* __restrict__ xb, const ushort_t* __restrict__ wT,
                         const float* __restrict__ bias,
                         ushort_t* __restrict__ qw, ushort_t* __restrict__ kw,
                         ushort_t* __restrict__ vt) {
    const int K = C_;
    __shared__ ushort_t As[128 * 64];   // 16KB, rows of 128B (linear for glds)
    __shared__ ushort_t Bs[128 * 64];
    const int tid = threadIdx.x, lane = tid & 63, wid = tid >> 6;
    const int cl = lane & 15, gl = lane >> 4;
    const int waveM = wid >> 1, waveN = wid & 1;
    const int m0 = blockIdx.y * 128, n0 = blockIdx.x * 128;
    const int srow = tid >> 3, scq = tid & 7;   // row 0..31 (+32i), 16B chunk 0..7

    f32x4 acc[4][4];
    #pragma unroll
    for (int mf = 0; mf < 4; mf++)
        #pragma unroll
        for (int nf = 0; nf < 4; nf++) acc[mf][nf] = (f32x4)0.0f;

    for (int kk = 0; kk < K; kk += 64) {
        #pragma unroll
        for (int i = 0; i < 4; i++) {
            int row = srow + i * 32;
            glds16(&xb[(size_t)(m0 + row) * K + kk + scq * 8], &As[row * 64 + scq * 8]);
            glds16(&wT[(size_t)(n0 + row) * K + kk + scq * 8], &Bs[row * 64 + scq * 8]);
        }
        __syncthreads();
        bf16x8 a[2][4], b[2][4];
        #pragma unroll
        for (int ks = 0; ks < 2; ks++) {
            #pragma unroll
            for (int mf = 0; mf < 4; mf++)
                a[ks][mf] = *(bf16x8*)&As[(waveM * 64 + mf * 16 + cl) * 64 + ks * 32 + gl * 8];
            #pragma unroll
            for (int nf = 0; nf < 4; nf++)
                b[ks][nf] = *(bf16x8*)&Bs[(waveN * 64 + nf * 16 + cl) * 64 + ks * 32 + gl * 8];
        }
        #pragma unroll
        for (int ks = 0; ks < 2; ks++)
            #pragma unroll
            for (int mf = 0; mf < 4; mf++)
                #pragma unroll
                for (int nf = 0; nf < 4; nf++)
                    acc[mf][nf] = __builtin_amdgcn_mfma_f32_16x16x32_bf16(a[ks][mf], b[ks][nf], acc[mf][nf], 0, 0, 0);
        __syncthreads();
    }
    const int secb = n0 >> 10;                // uniform per block
    #pragma unroll
    for (int mf = 0; mf < 4; mf++)
        #pragma unroll
        for (int nf = 0; nf < 4; nf++)
            #pragma unroll
            for (int r = 0; r < 4; r++) {
                int rg = m0 + waveM * 64 + mf * 16 + 4 * gl + r;
                int cg = n0 + waveN * 64 + nf * 16 + cl;
                float val = acc[mf][nf][r] + bias[cg];
                int cc = cg & 1023;
                int h = cc >> 6, hs = cc & 63;
                int bb = rg >> 11, tq = rg & 2047;
                if (secb == 0)
                    qw[(((size_t)(bb * H_ + h)) * T_ + tq) * HS_ + hs] = f2bf(val * QSCALE);
                else if (secb == 1)
                    kw[(((size_t)(bb * H_ + h)) * T_ + tq) * HS_ + hs] = f2bf(val);
                else
                    vt[(((size_t)(bb * H_ + h)) * HS_ + hs) * T_ + tq] = f2bf(val);
            }
}

// ---------------- MFMA flash attention v3: KVBLK=128 + defer-max ----------------
// Grid (8, 64), 512 threads = 8 waves x 16 q-rows; qt-pairing {qp, 15-qp}; 128-wide kv tiles.
__launch_bounds__(512, 4)
__global__ void attn_mfma(const ushort_t* __restrict__ qw,
                          const ushort_t* __restrict__ kw,
                          const ushort_t* __restrict__ vt,
                          ushort_t* __restrict__ yw) {
    __shared__ ushort_t Ks[128][72];         // 18.4KB
    __shared__ ushort_t Vts[64][136];        // 17.4KB  (d x kvlocal)
    __shared__ ushort_t Ps[8][16][136];      // 34.8KB  per-wave P (16 q x 128 kv)
    const int tid = threadIdx.x, lane = tid & 63, wid = tid >> 6;
    const int cl = lane & 15, gl = lane >> 4;
    const int qp = blockIdx.x;               // 0..7
    const int bh = blockIdx.y;               // 0..63
    const size_t base = (size_t)bh * T_ * HS_;
    const int bq = bh >> 4, h = bh & 15;
    const int srow = tid >> 3, scq = tid & 7;    // staging: row 0..63, 16B chunk 0..7

    for (int half = 0; half < 2; half++) {
        const int qt = half ? (15 - qp) : qp;
        const int q0 = qt * 128 + wid * 16;      // wave's first q row (q0 >= kt*128 for all kt)
        const int ntiles = qt + 1;               // 128-wide kv tiles

        // Q fragments (B-operand): row=cl -> q, k=8gl+j (Q prescaled by QSCALE)
        bf16x8 qf[2];
        #pragma unroll
        for (int kh = 0; kh < 2; kh++)
            qf[kh] = *(const bf16x8*)&qw[base + (size_t)(q0 + cl) * HS_ + kh * 32 + 8 * gl];

        f32x4 o_acc[4];
        #pragma unroll
        for (int dn = 0; dn < 4; dn++) o_acc[dn] = (f32x4)0.0f;
        float m_ = -INFINITY, l_ = 0.f;

        // prologue prefetch (tile 0)
        bf16x8 kpre[2], vpre[2], knew[2], vnew[2];
        kpre[0] = *(const bf16x8*)&kw[base + (size_t)srow * HS_ + scq * 8];
        kpre[1] = *(const bf16x8*)&kw[base + (size_t)(64 + srow) * HS_ + scq * 8];
        vpre[0] = *(const bf16x8*)&vt[base + (size_t)srow * T_ + scq * 8];
        vpre[1] = *(const bf16x8*)&vt[base + (size_t)srow * T_ + 64 + scq * 8];

        for (int kt = 0; kt < ntiles; kt++) {
            __syncthreads();
            if (kt + 1 < ntiles) {   // issue next tile's loads early (hide under compute)
                knew[0] = *(const bf16x8*)&kw[base + (size_t)((kt + 1) * 128 + srow) * HS_ + scq * 8];
                knew[1] = *(const bf16x8*)&kw[base + (size_t)((kt + 1) * 128 + 64 + srow) * HS_ + scq * 8];
                vnew[0] = *(const bf16x8*)&vt[base + (size_t)srow * T_ + (kt + 1) * 128 + scq * 8];
                vnew[1] = *(const bf16x8*)&vt[base + (size_t)srow * T_ + (kt + 1) * 128 + 64 + scq * 8];
            }
            *(bf16x8*)&Ks[srow][scq * 8] = kpre[0];
            *(bf16x8*)&Ks[64 + srow][scq * 8] = kpre[1];
            *(bf16x8*)&Vts[srow][scq * 8] = vpre[0];
            *(bf16x8*)&Vts[srow][scq * 8 + 64] = vpre[1];
            __syncthreads();

            {
                const bool full = (kt * 128 + 127 <= q0);

                // S^T = K Q^T : lane holds S[kv=kt*128+kn*16+4gl+r][q=cl]
                f32x4 st[8];
                #pragma unroll
                for (int kn = 0; kn < 8; kn++) {
                    bf16x8 kf0 = *(bf16x8*)&Ks[kn * 16 + cl][8 * gl];
                    bf16x8 kf1 = *(bf16x8*)&Ks[kn * 16 + cl][32 + 8 * gl];
                    f32x4 t0 = (f32x4)0.0f;
                    t0 = __builtin_amdgcn_mfma_f32_16x16x32_bf16(kf0, qf[0], t0, 0, 0, 0);
                    st[kn] = __builtin_amdgcn_mfma_f32_16x16x32_bf16(kf1, qf[1], t0, 0, 0, 0);
                }
                if (!full) {
                    const int qg = q0 + cl;
                    #pragma unroll
                    for (int kn = 0; kn < 8; kn++)
                        #pragma unroll
                        for (int r = 0; r < 4; r++) {
                            int kv = kt * 128 + kn * 16 + 4 * gl + r;
                            if (kv > qg) st[kn][r] = -INFINITY;
                        }
                }

                // per-lane partial max (31 ops), defer-max check (no reduce on pass path)
                float pmax = st[0][0];
                #pragma unroll
                for (int kn = 0; kn < 8; kn++)
                    #pragma unroll
                    for (int r = 0; r < 4; r++) pmax = fmaxf(pmax, st[kn][r]);
                if (!__all(pmax <= m_ + 8.0f)) {     // rare after first tile
                    float mx = pmax;
                    mx = fmaxf(mx, __shfl_xor(mx, 16));
                    mx = fmaxf(mx, __shfl_xor(mx, 32));
                    float nm = fmaxf(m_, mx);        // finite (every row has kv=0 unmasked)
                    float al = exp2f(m_ - nm);       // m_=-inf first tile -> 0
                    l_ *= al;
                    #pragma unroll
                    for (int r = 0; r < 4; r++) {
                        float ag = __shfl(al, 4 * gl + r);
                        #pragma unroll
                        for (int dn = 0; dn < 4; dn++) o_acc[dn][r] *= ag;
                    }
                    m_ = nm;
                }

                // P = exp2(S - m_) (bounded by 2^8), partial row-sum, pack bf16
                float ps = 0.f;
                #pragma unroll
                for (int kn = 0; kn < 8; kn++) {
                    float p0 = exp2f(st[kn][0] - m_);
                    float p1 = exp2f(st[kn][1] - m_);
                    float p2 = exp2f(st[kn][2] - m_);
                    float p3 = exp2f(st[kn][3] - m_);
                    ps += (p0 + p1) + (p2 + p3);
                    unsigned lo, hi;
                    asm("v_cvt_pk_bf16_f32 %0, %1, %2" : "=v"(lo) : "v"(p0), "v"(p1));
                    asm("v_cvt_pk_bf16_f32 %0, %1, %2" : "=v"(hi) : "v"(p2), "v"(p3));
                    uint2 wv; wv.x = lo; wv.y = hi;
                    *(uint2*)&Ps[wid][cl][kn * 16 + 4 * gl] = wv;    // ds_write_b64, same-wave
                }
                l_ += ps;

                // O += P V
                bf16x8 pf[4];
                #pragma unroll
                for (int ks = 0; ks < 4; ks++)
                    pf[ks] = *(bf16x8*)&Ps[wid][cl][ks * 32 + 8 * gl];
                #pragma unroll
                for (int dn = 0; dn < 4; dn++)
                    #pragma unroll
                    for (int ks = 0; ks < 4; ks++) {
                        bf16x8 vf = *(bf16x8*)&Vts[dn * 16 + cl][ks * 32 + 8 * gl];
                        o_acc[dn] = __builtin_amdgcn_mfma_f32_16x16x32_bf16(pf[ks], vf, o_acc[dn], 0, 0, 0);
                    }
            }
            #pragma unroll
            for (int i = 0; i < 2; i++) { kpre[i] = knew[i]; vpre[i] = vnew[i]; }
        }

        // total l over gl groups, normalize, write y [B,T,C]
        float ls = l_;
        ls += __shfl_xor(ls, 16);
        ls += __shfl_xor(ls, 32);
        float linv = 1.0f / ls;
        #pragma unroll
        for (int r = 0; r < 4; r++) {
            float lr = __shfl(linv, 4 * gl + r);
            int qg = q0 + 4 * gl + r;
            #pragma unroll
            for (int dn = 0; dn < 4; dn++) {
                int d = dn * 16 + cl;
                yw[((size_t)(bq * T_ + qg)) * C_ + h * HS_ + d] = f2bf(o_acc[dn][r] * lr);
            }
        }
    }
}

// ---------------- Output projection: BK=64, 128x128 tile ----------------
__launch_bounds__(256)
__global__ void proj_gemm(const ushort_t* __restrict__ y, const ushort_t* __restrict__ wT,
                          const float* __restrict__ bias, float* __restrict__ out) {
    const int K = C_, N = C_;
    __shared__ ushort_t As[128 * 64];
    __shared__ ushort_t Bs[128 * 64];
    const int tid = threadIdx.x, lane = tid & 63, wid = tid >> 6;
    const int cl = lane & 15, gl = lane >> 4;
    const int waveM = wid >> 1, waveN = wid & 1;
    const int m0 = blockIdx.y * 128, n0 = blockIdx.x * 128;
    const int srow = tid >> 3, scq = tid & 7;

    f32x4 acc[4][4];
    #pragma unroll
    for (int mf = 0; mf < 4; mf++)
        #pragma unroll
        for (int nf = 0; nf < 4; nf++) acc[mf][nf] = (f32x4)0.0f;

    for (int kk = 0; kk < K; kk += 64) {
        #pragma unroll
        for (int i = 0; i < 4; i++) {
            int row = srow + i * 32;
            glds16(&y[(size_t)(m0 + row) * K + kk + scq * 8], &As[row * 64 + scq * 8]);
            glds16(&wT[(size_t)(n0 + row) * K + kk + scq * 8], &Bs[row * 64 + scq * 8]);
        }
        __syncthreads();
        bf16x8 a[2][4], b[2][4];
        #pragma unroll
        for (int ks = 0; ks < 2; ks++) {
            #pragma unroll
            for (int mf = 0; mf < 4; mf++)
                a[ks][mf] = *(bf16x8*)&As[(waveM * 64 + mf * 16 + cl) * 64 + ks * 32 + gl * 8];
            #pragma unroll
            for (int nf = 0; nf < 4; nf++)
                b[ks][nf] = *(bf16x8*)&Bs[(waveN * 64 + nf * 16 + cl) * 64 + ks * 32 + gl * 8];
        }
        #pragma unroll
        for (int ks = 0; ks < 2; ks++)
            #pragma unroll
            for (int mf = 0; mf < 4; mf++)
                #pragma unroll
                for (int nf = 0; nf < 4; nf++)
                    acc[mf][nf] = __builtin_amdgcn_mfma_f32_16x16x32_bf16(a[ks][mf], b[ks][nf], acc[mf][nf], 0, 0, 0);
        __syncthreads();
    }
    #pragma unroll
    for (int mf = 0; mf < 4; mf++)
        #pragma unroll
        for (int nf = 0; nf < 4; nf++)
            #pragma unroll
            for (int r = 0; r < 4; r++) {
                int rg = m0 + waveM * 64 + mf * 16 + 4 * gl + r;
                int cg = n0 + waveN * 64 + nf * 16 + cl;
                out[(size_t)rg * N + cg] = acc[mf][nf][r] + bias[cg];
            }
}

extern "C" void kernel_launch(void* const* d_in, const int* in_sizes, int n_in,
                              void* d_out, int out_size, void* d_ws, size_t ws_size,
                              hipStream_t stream) {
    const float* x      = (const float*)d_in[0];
    const float* w_attn = (const float*)d_in[1];
    const float* b_attn = (const float*)d_in[2];
    const float* w_proj = (const float*)d_in[3];
    const float* b_proj = (const float*)d_in[4];
    float* out = (float*)d_out;

    const size_t E = (size_t)M_ * C_;   // 8388608
    ushort_t* qw  = (ushort_t*)d_ws;
    ushort_t* kw  = qw + E;
    ushort_t* vt  = kw + E;             // [B,H,HS,T]
    ushort_t* xy  = vt + E;             // xb during qkv, then yw [B,T,C]
    ushort_t* wat = xy + E;             // w_attn^T [3072][1024]
    ushort_t* wpt = vt;                 // w_proj^T reuses vt slot after attn

    cvt_x<<<dim3(4096), 256, 0, stream>>>(x, xy);
    transpose_cvt<<<dim3(48, 16), 256, 0, stream>>>(w_attn, wat, C_, 3 * C_);
    qkv_gemm<<<dim3(24, 64), 256, 0, stream>>>(xy, wat, b_attn, qw, kw, vt);
    attn_mfma<<<dim3(8, 64), 512, 0, stream>>>(qw, kw, vt, xy);
    transpose_cvt<<<dim3(16, 16), 256, 0, stream>>>(w_proj, wpt, C_, C_);
    proj_gemm<<<dim3(8, 64), 256, 0, stream>>>(xy, wpt, b_proj, out);
}

// Round 8
// 297.724 us; speedup vs baseline: 1.0342x; 1.0342x over previous
//
#include <hip/hip_runtime.h>
#include <hip/hip_bf16.h>

// Problem: B=4, T=2048, C=1024, H=16, HS=64. M = B*T = 8192.
#define B_ 4
#define T_ 2048
#define C_ 1024
#define H_ 16
#define HS_ 64
#define M_ (B_*T_)
#define QSCALE 0.18033688011112042f   // 0.125 * log2(e): softmax in exp2 domain

typedef __bf16 bf16_t;
typedef bf16_t bf16x8 __attribute__((ext_vector_type(8)));
typedef float f32x4 __attribute__((ext_vector_type(4)));
typedef unsigned short ushort_t;

__device__ __forceinline__ unsigned short f2bf(float f) {
    __hip_bfloat16 h = __float2bfloat16(f);
    return __builtin_bit_cast(unsigned short, h);
}

__device__ __forceinline__ void glds16(const void* g, void* l) {
    __builtin_amdgcn_global_load_lds((const __attribute__((address_space(1))) void*)g,
                                     (__attribute__((address_space(3))) void*)l, 16, 0, 0);
}

// ---------------- prep: x fp32 -> bf16 row-major ----------------
__launch_bounds__(256)
__global__ void cvt_x(const float* __restrict__ in, ushort_t* __restrict__ out) {
    int i = blockIdx.x * 256 + threadIdx.x;   // 8 elems per thread
    const float4* p = (const float4*)in;
    float4 a = p[i * 2], b = p[i * 2 + 1];
    ushort4 o0, o1;
    o0.x = f2bf(a.x); o0.y = f2bf(a.y); o0.z = f2bf(a.z); o0.w = f2bf(a.w);
    o1.x = f2bf(b.x); o1.y = f2bf(b.y); o1.z = f2bf(b.z); o1.w = f2bf(b.w);
    *(ushort4*)&out[i * 8] = o0;
    *(ushort4*)&out[i * 8 + 4] = o1;
}

// ---------------- prep: w [K][N] fp32 -> wT [N][K] bf16 (64x64 LDS tiles) ----------------
__launch_bounds__(256)
__global__ void transpose_cvt(const float* __restrict__ w, ushort_t* __restrict__ wT,
                              int K, int N) {
    __shared__ ushort_t Ts[64][72];
    const int n0 = blockIdx.x * 64, k0 = blockIdx.y * 64;
    const int t = threadIdx.x, r = t >> 2, cq = t & 3;
    #pragma unroll
    for (int j = 0; j < 4; j++) {
        float4 v = *(const float4*)&w[(size_t)(k0 + r) * N + n0 + cq * 16 + j * 4];
        ushort4 o;
        o.x = f2bf(v.x); o.y = f2bf(v.y); o.z = f2bf(v.z); o.w = f2bf(v.w);
        *(ushort4*)&Ts[r][cq * 16 + j * 4] = o;
    }
    __syncthreads();
    #pragma unroll
    for (int j = 0; j < 4; j++) {
        ushort4 o;
        o.x = Ts[cq * 16 + j * 4 + 0][r];
        o.y = Ts[cq * 16 + j * 4 + 1][r];
        o.z = Ts[cq * 16 + j * 4 + 2][r];
        o.w = Ts[cq * 16 + j * 4 + 3][r];
        *(ushort4*)&wT[(size_t)(n0 + r) * K + k0 + cq * 16 + j * 4] = o;
    }
}

// ---------------- QKV GEMM: BK=32, dbuf LDS, swizzled staging (rule-21 pattern) ----------------
// Q -> [B,H,T,HS] PRESCALED by QSCALE; K -> [B,H,T,HS]; V -> transposed [B,H,HS,T].
__launch_bounds__(256)
__global__ void qkv_gemm(const ushort_t* __restrict__ xb, const ushort_t* __restrict__ wT,
                         const float* __restrict__ bias,
                         ushort_t* __restrict__ qw, ushort_t* __restrict__ kw,
                         ushort_t* __restrict__ vt) {
    const int K = C_;
    __shared__ ushort_t As[2][128 * 32];   // 2 x 8KB, 64B rows, linear (glds dest)
    __shared__ ushort_t Bs[2][128 * 32];
    const int tid = threadIdx.x, lane = tid & 63, wid = tid >> 6;
    const int cl = lane & 15, gl = lane >> 4;
    const int waveM = wid >> 1, waveN = wid & 1;
    const int m0 = blockIdx.y * 128, n0 = blockIdx.x * 128;
    const int srow = tid >> 2, scq = tid & 3;            // staging: row 0..63 (+64i), chunk 0..3
    const int gsw = scq ^ ((srow >> 1) & 3);             // pre-swizzled global chunk
    const int asw = 8 * (gl ^ ((cl >> 1) & 3));          // swizzled read chunk offset (elems)

    f32x4 acc[4][4];
    #pragma unroll
    for (int mf = 0; mf < 4; mf++)
        #pragma unroll
        for (int nf = 0; nf < 4; nf++) acc[mf][nf] = (f32x4)0.0f;

    // prologue: stage tile 0 into buf 0
    #pragma unroll
    for (int i = 0; i < 2; i++) {
        int row = srow + i * 64;
        glds16(&xb[(size_t)(m0 + row) * K + gsw * 8], &As[0][row * 32 + scq * 8]);
        glds16(&wT[(size_t)(n0 + row) * K + gsw * 8], &Bs[0][row * 32 + scq * 8]);
    }
    __syncthreads();

    int cur = 0;
    for (int kk = 0; kk < K; kk += 32) {
        if (kk + 32 < K) {       // issue next tile's loads BEFORE compute (in-flight overlap)
            #pragma unroll
            for (int i = 0; i < 2; i++) {
                int row = srow + i * 64;
                glds16(&xb[(size_t)(m0 + row) * K + kk + 32 + gsw * 8], &As[cur ^ 1][row * 32 + scq * 8]);
                glds16(&wT[(size_t)(n0 + row) * K + kk + 32 + gsw * 8], &Bs[cur ^ 1][row * 32 + scq * 8]);
            }
        }
        bf16x8 a[4], b[4];
        #pragma unroll
        for (int mf = 0; mf < 4; mf++)
            a[mf] = *(bf16x8*)&As[cur][(waveM * 64 + mf * 16 + cl) * 32 + asw];
        #pragma unroll
        for (int nf = 0; nf < 4; nf++)
            b[nf] = *(bf16x8*)&Bs[cur][(waveN * 64 + nf * 16 + cl) * 32 + asw];
        #pragma unroll
        for (int mf = 0; mf < 4; mf++)
            #pragma unroll
            for (int nf = 0; nf < 4; nf++)
                acc[mf][nf] = __builtin_amdgcn_mfma_f32_16x16x32_bf16(a[mf], b[nf], acc[mf][nf], 0, 0, 0);
        __syncthreads();         // drains staging; publishes buf cur^1
        cur ^= 1;
    }
    const int secb = n0 >> 10;                // uniform per block
    #pragma unroll
    for (int mf = 0; mf < 4; mf++)
        #pragma unroll
        for (int nf = 0; nf < 4; nf++)
            #pragma unroll
            for (int r = 0; r < 4; r++) {
                int rg = m0 + waveM * 64 + mf * 16 + 4 * gl + r;
                int cg = n0 + waveN * 64 + nf * 16 + cl;
                float val = acc[mf][nf][r] + bias[cg];
                int cc = cg & 1023;
                int h = cc >> 6, hs = cc & 63;
                int bb = rg >> 11, tq = rg & 2047;
                if (secb == 0)
                    qw[(((size_t)(bb * H_ + h)) * T_ + tq) * HS_ + hs] = f2bf(val * QSCALE);
                else if (secb == 1)
                    kw[(((size_t)(bb * H_ + h)) * T_ + tq) * HS_ + hs] = f2bf(val);
                else
                    vt[(((size_t)(bb * H_ + h)) * HS_ + hs) * T_ + tq] = f2bf(val);
            }
}

// ---------------- MFMA flash attention v3: KVBLK=128 + defer-max (unchanged) ----------------
__launch_bounds__(512, 4)
__global__ void attn_mfma(const ushort_t* __restrict__ qw,
                          const ushort_t* __restrict__ kw,
                          const ushort_t* __restrict__ vt,
                          ushort_t* __restrict__ yw) {
    __shared__ ushort_t Ks[128][72];
    __shared__ ushort_t Vts[64][136];
    __shared__ ushort_t Ps[8][16][136];
    const int tid = threadIdx.x, lane = tid & 63, wid = tid >> 6;
    const int cl = lane & 15, gl = lane >> 4;
    const int qp = blockIdx.x;               // 0..7
    const int bh = blockIdx.y;               // 0..63
    const size_t base = (size_t)bh * T_ * HS_;
    const int bq = bh >> 4, h = bh & 15;
    const int srow = tid >> 3, scq = tid & 7;

    for (int half = 0; half < 2; half++) {
        const int qt = half ? (15 - qp) : qp;
        const int q0 = qt * 128 + wid * 16;
        const int ntiles = qt + 1;

        bf16x8 qf[2];
        #pragma unroll
        for (int kh = 0; kh < 2; kh++)
            qf[kh] = *(const bf16x8*)&qw[base + (size_t)(q0 + cl) * HS_ + kh * 32 + 8 * gl];

        f32x4 o_acc[4];
        #pragma unroll
        for (int dn = 0; dn < 4; dn++) o_acc[dn] = (f32x4)0.0f;
        float m_ = -INFINITY, l_ = 0.f;

        bf16x8 kpre[2], vpre[2], knew[2], vnew[2];
        kpre[0] = *(const bf16x8*)&kw[base + (size_t)srow * HS_ + scq * 8];
        kpre[1] = *(const bf16x8*)&kw[base + (size_t)(64 + srow) * HS_ + scq * 8];
        vpre[0] = *(const bf16x8*)&vt[base + (size_t)srow * T_ + scq * 8];
        vpre[1] = *(const bf16x8*)&vt[base + (size_t)srow * T_ + 64 + scq * 8];

        for (int kt = 0; kt < ntiles; kt++) {
            __syncthreads();
            if (kt + 1 < ntiles) {
                knew[0] = *(const bf16x8*)&kw[base + (size_t)((kt + 1) * 128 + srow) * HS_ + scq * 8];
                knew[1] = *(const bf16x8*)&kw[base + (size_t)((kt + 1) * 128 + 64 + srow) * HS_ + scq * 8];
                vnew[0] = *(const bf16x8*)&vt[base + (size_t)srow * T_ + (kt + 1) * 128 + scq * 8];
                vnew[1] = *(const bf16x8*)&vt[base + (size_t)srow * T_ + (kt + 1) * 128 + 64 + scq * 8];
            }
            *(bf16x8*)&Ks[srow][scq * 8] = kpre[0];
            *(bf16x8*)&Ks[64 + srow][scq * 8] = kpre[1];
            *(bf16x8*)&Vts[srow][scq * 8] = vpre[0];
            *(bf16x8*)&Vts[srow][scq * 8 + 64] = vpre[1];
            __syncthreads();

            {
                const bool full = (kt * 128 + 127 <= q0);

                f32x4 st[8];
                #pragma unroll
                for (int kn = 0; kn < 8; kn++) {
                    bf16x8 kf0 = *(bf16x8*)&Ks[kn * 16 + cl][8 * gl];
                    bf16x8 kf1 = *(bf16x8*)&Ks[kn * 16 + cl][32 + 8 * gl];
                    f32x4 t0 = (f32x4)0.0f;
                    t0 = __builtin_amdgcn_mfma_f32_16x16x32_bf16(kf0, qf[0], t0, 0, 0, 0);
                    st[kn] = __builtin_amdgcn_mfma_f32_16x16x32_bf16(kf1, qf[1], t0, 0, 0, 0);
                }
                if (!full) {
                    const int qg = q0 + cl;
                    #pragma unroll
                    for (int kn = 0; kn < 8; kn++)
                        #pragma unroll
                        for (int r = 0; r < 4; r++) {
                            int kv = kt * 128 + kn * 16 + 4 * gl + r;
                            if (kv > qg) st[kn][r] = -INFINITY;
                        }
                }

                float pmax = st[0][0];
                #pragma unroll
                for (int kn = 0; kn < 8; kn++)
                    #pragma unroll
                    for (int r = 0; r < 4; r++) pmax = fmaxf(pmax, st[kn][r]);
                if (!__all(pmax <= m_ + 8.0f)) {
                    float mx = pmax;
                    mx = fmaxf(mx, __shfl_xor(mx, 16));
                    mx = fmaxf(mx, __shfl_xor(mx, 32));
                    float nm = fmaxf(m_, mx);
                    float al = exp2f(m_ - nm);
                    l_ *= al;
                    #pragma unroll
                    for (int r = 0; r < 4; r++) {
                        float ag = __shfl(al, 4 * gl + r);
                        #pragma unroll
                        for (int dn = 0; dn < 4; dn++) o_acc[dn][r] *= ag;
                    }
                    m_ = nm;
                }

                float ps = 0.f;
                #pragma unroll
                for (int kn = 0; kn < 8; kn++) {
                    float p0 = exp2f(st[kn][0] - m_);
                    float p1 = exp2f(st[kn][1] - m_);
                    float p2 = exp2f(st[kn][2] - m_);
                    float p3 = exp2f(st[kn][3] - m_);
                    ps += (p0 + p1) + (p2 + p3);
                    unsigned lo, hi;
                    asm("v_cvt_pk_bf16_f32 %0, %1, %2" : "=v"(lo) : "v"(p0), "v"(p1));
                    asm("v_cvt_pk_bf16_f32 %0, %1, %2" : "=v"(hi) : "v"(p2), "v"(p3));
                    uint2 wv; wv.x = lo; wv.y = hi;
                    *(uint2*)&Ps[wid][cl][kn * 16 + 4 * gl] = wv;
                }
                l_ += ps;

                bf16x8 pf[4];
                #pragma unroll
                for (int ks = 0; ks < 4; ks++)
                    pf[ks] = *(bf16x8*)&Ps[wid][cl][ks * 32 + 8 * gl];
                #pragma unroll
                for (int dn = 0; dn < 4; dn++)
                    #pragma unroll
                    for (int ks = 0; ks < 4; ks++) {
                        bf16x8 vf = *(bf16x8*)&Vts[dn * 16 + cl][ks * 32 + 8 * gl];
                        o_acc[dn] = __builtin_amdgcn_mfma_f32_16x16x32_bf16(pf[ks], vf, o_acc[dn], 0, 0, 0);
                    }
            }
            #pragma unroll
            for (int i = 0; i < 2; i++) { kpre[i] = knew[i]; vpre[i] = vnew[i]; }
        }

        float ls = l_;
        ls += __shfl_xor(ls, 16);
        ls += __shfl_xor(ls, 32);
        float linv = 1.0f / ls;
        #pragma unroll
        for (int r = 0; r < 4; r++) {
            float lr = __shfl(linv, 4 * gl + r);
            int qg = q0 + 4 * gl + r;
            #pragma unroll
            for (int dn = 0; dn < 4; dn++) {
                int d = dn * 16 + cl;
                yw[((size_t)(bq * T_ + qg)) * C_ + h * HS_ + d] = f2bf(o_acc[dn][r] * lr);
            }
        }
    }
}

// ---------------- Output projection: BK=32, dbuf, swizzled (same as qkv) ----------------
__launch_bounds__(256)
__global__ void proj_gemm(const ushort_t* __restrict__ y, const ushort_t* __restrict__ wT,
                          const float* __restrict__ bias, float* __restrict__ out) {
    const int K = C_, N = C_;
    __shared__ ushort_t As[2][128 * 32];
    __shared__ ushort_t Bs[2][128 * 32];
    const int tid = threadIdx.x, lane = tid & 63, wid = tid >> 6;
    const int cl = lane & 15, gl = lane >> 4;
    const int waveM = wid >> 1, waveN = wid & 1;
    const int m0 = blockIdx.y * 128, n0 = blockIdx.x * 128;
    const int srow = tid >> 2, scq = tid & 3;
    const int gsw = scq ^ ((srow >> 1) & 3);
    const int asw = 8 * (gl ^ ((cl >> 1) & 3));

    f32x4 acc[4][4];
    #pragma unroll
    for (int mf = 0; mf < 4; mf++)
        #pragma unroll
        for (int nf = 0; nf < 4; nf++) acc[mf][nf] = (f32x4)0.0f;

    #pragma unroll
    for (int i = 0; i < 2; i++) {
        int row = srow + i * 64;
        glds16(&y[(size_t)(m0 + row) * K + gsw * 8], &As[0][row * 32 + scq * 8]);
        glds16(&wT[(size_t)(n0 + row) * K + gsw * 8], &Bs[0][row * 32 + scq * 8]);
    }
    __syncthreads();

    int cur = 0;
    for (int kk = 0; kk < K; kk += 32) {
        if (kk + 32 < K) {
            #pragma unroll
            for (int i = 0; i < 2; i++) {
                int row = srow + i * 64;
                glds16(&y[(size_t)(m0 + row) * K + kk + 32 + gsw * 8], &As[cur ^ 1][row * 32 + scq * 8]);
                glds16(&wT[(size_t)(n0 + row) * K + kk + 32 + gsw * 8], &Bs[cur ^ 1][row * 32 + scq * 8]);
            }
        }
        bf16x8 a[4], b[4];
        #pragma unroll
        for (int mf = 0; mf < 4; mf++)
            a[mf] = *(bf16x8*)&As[cur][(waveM * 64 + mf * 16 + cl) * 32 + asw];
        #pragma unroll
        for (int nf = 0; nf < 4; nf++)
            b[nf] = *(bf16x8*)&Bs[cur][(waveN * 64 + nf * 16 + cl) * 32 + asw];
        #pragma unroll
        for (int mf = 0; mf < 4; mf++)
            #pragma unroll
            for (int nf = 0; nf < 4; nf++)
                acc[mf][nf] = __builtin_amdgcn_mfma_f32_16x16x32_bf16(a[mf], b[nf], acc[mf][nf], 0, 0, 0);
        __syncthreads();
        cur ^= 1;
    }
    #pragma unroll
    for (int mf = 0; mf < 4; mf++)
        #pragma unroll
        for (int nf = 0; nf < 4; nf++)
            #pragma unroll
            for (int r = 0; r < 4; r++) {
                int rg = m0 + waveM * 64 + mf * 16 + 4 * gl + r;
                int cg = n0 + waveN * 64 + nf * 16 + cl;
                out[(size_t)rg * N + cg] = acc[mf][nf][r] + bias[cg];
            }
}

extern "C" void kernel_launch(void* const* d_in, const int* in_sizes, int n_in,
                              void* d_out, int out_size, void* d_ws, size_t ws_size,
                              hipStream_t stream) {
    const float* x      = (const float*)d_in[0];
    const float* w_attn = (const float*)d_in[1];
    const float* b_attn = (const float*)d_in[2];
    const float* w_proj = (const float*)d_in[3];
    const float* b_proj = (const float*)d_in[4];
    float* out = (float*)d_out;

    const size_t E = (size_t)M_ * C_;   // 8388608
    ushort_t* qw  = (ushort_t*)d_ws;
    ushort_t* kw  = qw + E;
    ushort_t* vt  = kw + E;             // [B,H,HS,T]
    ushort_t* xy  = vt + E;             // xb during qkv, then yw [B,T,C]
    ushort_t* wat = xy + E;             // w_attn^T [3072][1024]
    ushort_t* wpt = vt;                 // w_proj^T reuses vt slot after attn

    cvt_x<<<dim3(4096), 256, 0, stream>>>(x, xy);
    transpose_cvt<<<dim3(48, 16), 256, 0, stream>>>(w_attn, wat, C_, 3 * C_);
    qkv_gemm<<<dim3(24, 64), 256, 0, stream>>>(xy, wat, b_attn, qw, kw, vt);
    attn_mfma<<<dim3(8, 64), 512, 0, stream>>>(qw, kw, vt, xy);
    transpose_cvt<<<dim3(16, 16), 256, 0, stream>>>(w_proj, wpt, C_, C_);
    proj_gemm<<<dim3(8, 64), 256, 0, stream>>>(xy, wpt, b_proj, out);
}

// Round 9
// 293.013 us; speedup vs baseline: 1.0508x; 1.0161x over previous
//
#include <hip/hip_runtime.h>
#include <hip/hip_bf16.h>

// Problem: B=4, T=2048, C=1024, H=16, HS=64. M = B*T = 8192.
#define B_ 4
#define T_ 2048
#define C_ 1024
#define H_ 16
#define HS_ 64
#define M_ (B_*T_)
#define QSCALE 0.18033688011112042f   // 0.125 * log2(e): softmax in exp2 domain

typedef __bf16 bf16_t;
typedef bf16_t bf16x8 __attribute__((ext_vector_type(8)));
typedef float f32x4 __attribute__((ext_vector_type(4)));
typedef unsigned short ushort_t;

__device__ __forceinline__ unsigned short f2bf(float f) {
    __hip_bfloat16 h = __float2bfloat16(f);
    return __builtin_bit_cast(unsigned short, h);
}

__device__ __forceinline__ void glds16(const void* g, void* l) {
    __builtin_amdgcn_global_load_lds((const __attribute__((address_space(1))) void*)g,
                                     (__attribute__((address_space(3))) void*)l, 16, 0, 0);
}

// ---------------- prep: x fp32 -> bf16 row-major ----------------
__launch_bounds__(256)
__global__ void cvt_x(const float* __restrict__ in, ushort_t* __restrict__ out) {
    int i = blockIdx.x * 256 + threadIdx.x;   // 8 elems per thread
    const float4* p = (const float4*)in;
    float4 a = p[i * 2], b = p[i * 2 + 1];
    ushort4 o0, o1;
    o0.x = f2bf(a.x); o0.y = f2bf(a.y); o0.z = f2bf(a.z); o0.w = f2bf(a.w);
    o1.x = f2bf(b.x); o1.y = f2bf(b.y); o1.z = f2bf(b.z); o1.w = f2bf(b.w);
    *(ushort4*)&out[i * 8] = o0;
    *(ushort4*)&out[i * 8 + 4] = o1;
}

// ---------------- prep: w [K][N] fp32 -> wT [N][K] bf16 (64x64 LDS tiles) ----------------
__launch_bounds__(256)
__global__ void transpose_cvt(const float* __restrict__ w, ushort_t* __restrict__ wT,
                              int K, int N) {
    __shared__ ushort_t Ts[64][72];
    const int n0 = blockIdx.x * 64, k0 = blockIdx.y * 64;
    const int t = threadIdx.x, r = t >> 2, cq = t & 3;
    #pragma unroll
    for (int j = 0; j < 4; j++) {
        float4 v = *(const float4*)&w[(size_t)(k0 + r) * N + n0 + cq * 16 + j * 4];
        ushort4 o;
        o.x = f2bf(v.x); o.y = f2bf(v.y); o.z = f2bf(v.z); o.w = f2bf(v.w);
        *(ushort4*)&Ts[r][cq * 16 + j * 4] = o;
    }
    __syncthreads();
    #pragma unroll
    for (int j = 0; j < 4; j++) {
        ushort4 o;
        o.x = Ts[cq * 16 + j * 4 + 0][r];
        o.y = Ts[cq * 16 + j * 4 + 1][r];
        o.z = Ts[cq * 16 + j * 4 + 2][r];
        o.w = Ts[cq * 16 + j * 4 + 3][r];
        *(ushort4*)&wT[(size_t)(n0 + r) * K + k0 + cq * 16 + j * 4] = o;
    }
}

// ---------------- QKV GEMM: BK=32, 3-buf depth-2 pipeline, counted vmcnt ----------------
// Q -> [B,H,T,HS] PRESCALED by QSCALE; K -> [B,H,T,HS]; V -> transposed [B,H,HS,T].
__launch_bounds__(256)
__global__ void qkv_gemm(const ushort_t* __restrict__ xb, const ushort_t* __restrict__ wT,
                         const float* __restrict__ bias,
                         ushort_t* __restrict__ qw, ushort_t* __restrict__ kw,
                         ushort_t* __restrict__ vt) {
    const int K = C_;
    __shared__ ushort_t As[3][128 * 32];   // 3 x 8KB
    __shared__ ushort_t Bs[3][128 * 32];
    const int tid = threadIdx.x, lane = tid & 63, wid = tid >> 6;
    const int cl = lane & 15, gl = lane >> 4;
    const int waveM = wid >> 1, waveN = wid & 1;
    // XCD-aware swizzle: 1536 blocks, 192/XCD, row-major (bx fastest) within chunk
    const int bid = blockIdx.x;
    const int swz = (bid & 7) * 192 + (bid >> 3);
    const int by = swz / 24, bx = swz - by * 24;
    const int m0 = by * 128, n0 = bx * 128;
    const int srow = tid >> 2, scq = tid & 3;            // staging row 0..63 (+64), chunk 0..3
    const int gsw = scq ^ ((srow >> 1) & 3);             // pre-swizzled global chunk
    const int asw = 8 * (gl ^ ((cl >> 1) & 3));          // swizzled read offset (elems)

    f32x4 acc[4][4];
    #pragma unroll
    for (int mf = 0; mf < 4; mf++)
        #pragma unroll
        for (int nf = 0; nf < 4; nf++) acc[mf][nf] = (f32x4)0.0f;

    auto stage = [&](int t, int b) {
        const size_t koff = (size_t)t * 32 + gsw * 8;
        glds16(&xb[(size_t)(m0 + srow) * K + koff],      &As[b][srow * 32 + scq * 8]);
        glds16(&xb[(size_t)(m0 + srow + 64) * K + koff], &As[b][(srow + 64) * 32 + scq * 8]);
        glds16(&wT[(size_t)(n0 + srow) * K + koff],      &Bs[b][srow * 32 + scq * 8]);
        glds16(&wT[(size_t)(n0 + srow + 64) * K + koff], &Bs[b][(srow + 64) * 32 + scq * 8]);
    };
    stage(0, 0);
    stage(1, 1);

    int bk = 0;
    for (int ks = 0; ks < 32; ks++) {
        if (ks < 31) asm volatile("s_waitcnt vmcnt(4)" ::: "memory");  // tile ks landed; ks+1 in flight
        else         asm volatile("s_waitcnt vmcnt(0)" ::: "memory");
        __builtin_amdgcn_s_barrier();
        if (ks + 2 < 32) {
            int b2 = bk + 2; if (b2 >= 3) b2 -= 3;
            stage(ks + 2, b2);                 // issue early; lands ~2 iters later
        }
        bf16x8 a[4], b[4];
        #pragma unroll
        for (int mf = 0; mf < 4; mf++)
            a[mf] = *(bf16x8*)&As[bk][(waveM * 64 + mf * 16 + cl) * 32 + asw];
        #pragma unroll
        for (int nf = 0; nf < 4; nf++)
            b[nf] = *(bf16x8*)&Bs[bk][(waveN * 64 + nf * 16 + cl) * 32 + asw];
        #pragma unroll
        for (int mf = 0; mf < 4; mf++)
            #pragma unroll
            for (int nf = 0; nf < 4; nf++)
                acc[mf][nf] = __builtin_amdgcn_mfma_f32_16x16x32_bf16(a[mf], b[nf], acc[mf][nf], 0, 0, 0);
        bk = (bk == 2) ? 0 : bk + 1;
    }
    const int secb = n0 >> 10;                // uniform per block
    #pragma unroll
    for (int mf = 0; mf < 4; mf++)
        #pragma unroll
        for (int nf = 0; nf < 4; nf++)
            #pragma unroll
            for (int r = 0; r < 4; r++) {
                int rg = m0 + waveM * 64 + mf * 16 + 4 * gl + r;
                int cg = n0 + waveN * 64 + nf * 16 + cl;
                float val = acc[mf][nf][r] + bias[cg];
                int cc = cg & 1023;
                int h = cc >> 6, hs = cc & 63;
                int bb = rg >> 11, tq = rg & 2047;
                if (secb == 0)
                    qw[(((size_t)(bb * H_ + h)) * T_ + tq) * HS_ + hs] = f2bf(val * QSCALE);
                else if (secb == 1)
                    kw[(((size_t)(bb * H_ + h)) * T_ + tq) * HS_ + hs] = f2bf(val);
                else
                    vt[(((size_t)(bb * H_ + h)) * HS_ + hs) * T_ + tq] = f2bf(val);
            }
}

// ---------------- MFMA flash attention v3: KVBLK=128 + defer-max + setprio ----------------
__launch_bounds__(512, 4)
__global__ void attn_mfma(const ushort_t* __restrict__ qw,
                          const ushort_t* __restrict__ kw,
                          const ushort_t* __restrict__ vt,
                          ushort_t* __restrict__ yw) {
    __shared__ ushort_t Ks[128][72];
    __shared__ ushort_t Vts[64][136];
    __shared__ ushort_t Ps[8][16][136];
    const int tid = threadIdx.x, lane = tid & 63, wid = tid >> 6;
    const int cl = lane & 15, gl = lane >> 4;
    const int qp = blockIdx.x;               // 0..7
    const int bh = blockIdx.y;               // 0..63
    const size_t base = (size_t)bh * T_ * HS_;
    const int bq = bh >> 4, h = bh & 15;
    const int srow = tid >> 3, scq = tid & 7;

    for (int half = 0; half < 2; half++) {
        const int qt = half ? (15 - qp) : qp;
        const int q0 = qt * 128 + wid * 16;
        const int ntiles = qt + 1;

        bf16x8 qf[2];
        #pragma unroll
        for (int kh = 0; kh < 2; kh++)
            qf[kh] = *(const bf16x8*)&qw[base + (size_t)(q0 + cl) * HS_ + kh * 32 + 8 * gl];

        f32x4 o_acc[4];
        #pragma unroll
        for (int dn = 0; dn < 4; dn++) o_acc[dn] = (f32x4)0.0f;
        float m_ = -INFINITY, l_ = 0.f;

        bf16x8 kpre[2], vpre[2], knew[2], vnew[2];
        kpre[0] = *(const bf16x8*)&kw[base + (size_t)srow * HS_ + scq * 8];
        kpre[1] = *(const bf16x8*)&kw[base + (size_t)(64 + srow) * HS_ + scq * 8];
        vpre[0] = *(const bf16x8*)&vt[base + (size_t)srow * T_ + scq * 8];
        vpre[1] = *(const bf16x8*)&vt[base + (size_t)srow * T_ + 64 + scq * 8];

        for (int kt = 0; kt < ntiles; kt++) {
            __syncthreads();
            if (kt + 1 < ntiles) {
                knew[0] = *(const bf16x8*)&kw[base + (size_t)((kt + 1) * 128 + srow) * HS_ + scq * 8];
                knew[1] = *(const bf16x8*)&kw[base + (size_t)((kt + 1) * 128 + 64 + srow) * HS_ + scq * 8];
                vnew[0] = *(const bf16x8*)&vt[base + (size_t)srow * T_ + (kt + 1) * 128 + scq * 8];
                vnew[1] = *(const bf16x8*)&vt[base + (size_t)srow * T_ + (kt + 1) * 128 + 64 + scq * 8];
            }
            *(bf16x8*)&Ks[srow][scq * 8] = kpre[0];
            *(bf16x8*)&Ks[64 + srow][scq * 8] = kpre[1];
            *(bf16x8*)&Vts[srow][scq * 8] = vpre[0];
            *(bf16x8*)&Vts[srow][scq * 8 + 64] = vpre[1];
            __syncthreads();

            {
                const bool full = (kt * 128 + 127 <= q0);

                f32x4 st[8];
                __builtin_amdgcn_s_setprio(1);
                #pragma unroll
                for (int kn = 0; kn < 8; kn++) {
                    bf16x8 kf0 = *(bf16x8*)&Ks[kn * 16 + cl][8 * gl];
                    bf16x8 kf1 = *(bf16x8*)&Ks[kn * 16 + cl][32 + 8 * gl];
                    f32x4 t0 = (f32x4)0.0f;
                    t0 = __builtin_amdgcn_mfma_f32_16x16x32_bf16(kf0, qf[0], t0, 0, 0, 0);
                    st[kn] = __builtin_amdgcn_mfma_f32_16x16x32_bf16(kf1, qf[1], t0, 0, 0, 0);
                }
                __builtin_amdgcn_s_setprio(0);
                if (!full) {
                    const int qg = q0 + cl;
                    #pragma unroll
                    for (int kn = 0; kn < 8; kn++)
                        #pragma unroll
                        for (int r = 0; r < 4; r++) {
                            int kv = kt * 128 + kn * 16 + 4 * gl + r;
                            if (kv > qg) st[kn][r] = -INFINITY;
                        }
                }

                float pmax = st[0][0];
                #pragma unroll
                for (int kn = 0; kn < 8; kn++)
                    #pragma unroll
                    for (int r = 0; r < 4; r++) pmax = fmaxf(pmax, st[kn][r]);
                if (!__all(pmax <= m_ + 8.0f)) {
                    float mx = pmax;
                    mx = fmaxf(mx, __shfl_xor(mx, 16));
                    mx = fmaxf(mx, __shfl_xor(mx, 32));
                    float nm = fmaxf(m_, mx);
                    float al = exp2f(m_ - nm);
                    l_ *= al;
                    #pragma unroll
                    for (int r = 0; r < 4; r++) {
                        float ag = __shfl(al, 4 * gl + r);
                        #pragma unroll
                        for (int dn = 0; dn < 4; dn++) o_acc[dn][r] *= ag;
                    }
                    m_ = nm;
                }

                float ps = 0.f;
                #pragma unroll
                for (int kn = 0; kn < 8; kn++) {
                    float p0 = exp2f(st[kn][0] - m_);
                    float p1 = exp2f(st[kn][1] - m_);
                    float p2 = exp2f(st[kn][2] - m_);
                    float p3 = exp2f(st[kn][3] - m_);
                    ps += (p0 + p1) + (p2 + p3);
                    unsigned lo, hi;
                    asm("v_cvt_pk_bf16_f32 %0, %1, %2" : "=v"(lo) : "v"(p0), "v"(p1));
                    asm("v_cvt_pk_bf16_f32 %0, %1, %2" : "=v"(hi) : "v"(p2), "v"(p3));
                    uint2 wv; wv.x = lo; wv.y = hi;
                    *(uint2*)&Ps[wid][cl][kn * 16 + 4 * gl] = wv;
                }
                l_ += ps;

                bf16x8 pf[4];
                #pragma unroll
                for (int ks = 0; ks < 4; ks++)
                    pf[ks] = *(bf16x8*)&Ps[wid][cl][ks * 32 + 8 * gl];
                __builtin_amdgcn_s_setprio(1);
                #pragma unroll
                for (int dn = 0; dn < 4; dn++)
                    #pragma unroll
                    for (int ks = 0; ks < 4; ks++) {
                        bf16x8 vf = *(bf16x8*)&Vts[dn * 16 + cl][ks * 32 + 8 * gl];
                        o_acc[dn] = __builtin_amdgcn_mfma_f32_16x16x32_bf16(pf[ks], vf, o_acc[dn], 0, 0, 0);
                    }
                __builtin_amdgcn_s_setprio(0);
            }
            #pragma unroll
            for (int i = 0; i < 2; i++) { kpre[i] = knew[i]; vpre[i] = vnew[i]; }
        }

        float ls = l_;
        ls += __shfl_xor(ls, 16);
        ls += __shfl_xor(ls, 32);
        float linv = 1.0f / ls;
        #pragma unroll
        for (int r = 0; r < 4; r++) {
            float lr = __shfl(linv, 4 * gl + r);
            int qg = q0 + 4 * gl + r;
            #pragma unroll
            for (int dn = 0; dn < 4; dn++) {
                int d = dn * 16 + cl;
                yw[((size_t)(bq * T_ + qg)) * C_ + h * HS_ + d] = f2bf(o_acc[dn][r] * lr);
            }
        }
    }
}

// ---------------- Output projection: same 3-buf pipeline ----------------
__launch_bounds__(256)
__global__ void proj_gemm(const ushort_t* __restrict__ y, const ushort_t* __restrict__ wT,
                          const float* __restrict__ bias, float* __restrict__ out) {
    const int K = C_, N = C_;
    __shared__ ushort_t As[3][128 * 32];
    __shared__ ushort_t Bs[3][128 * 32];
    const int tid = threadIdx.x, lane = tid & 63, wid = tid >> 6;
    const int cl = lane & 15, gl = lane >> 4;
    const int waveM = wid >> 1, waveN = wid & 1;
    const int bid = blockIdx.x;              // 512 blocks
    const int swz = (bid & 7) * 64 + (bid >> 3);
    const int bx = swz & 7, by = swz >> 3;
    const int m0 = by * 128, n0 = bx * 128;
    const int srow = tid >> 2, scq = tid & 3;
    const int gsw = scq ^ ((srow >> 1) & 3);
    const int asw = 8 * (gl ^ ((cl >> 1) & 3));

    f32x4 acc[4][4];
    #pragma unroll
    for (int mf = 0; mf < 4; mf++)
        #pragma unroll
        for (int nf = 0; nf < 4; nf++) acc[mf][nf] = (f32x4)0.0f;

    auto stage = [&](int t, int b) {
        const size_t koff = (size_t)t * 32 + gsw * 8;
        glds16(&y[(size_t)(m0 + srow) * K + koff],       &As[b][srow * 32 + scq * 8]);
        glds16(&y[(size_t)(m0 + srow + 64) * K + koff],  &As[b][(srow + 64) * 32 + scq * 8]);
        glds16(&wT[(size_t)(n0 + srow) * K + koff],      &Bs[b][srow * 32 + scq * 8]);
        glds16(&wT[(size_t)(n0 + srow + 64) * K + koff], &Bs[b][(srow + 64) * 32 + scq * 8]);
    };
    stage(0, 0);
    stage(1, 1);

    int bk = 0;
    for (int ks = 0; ks < 32; ks++) {
        if (ks < 31) asm volatile("s_waitcnt vmcnt(4)" ::: "memory");
        else         asm volatile("s_waitcnt vmcnt(0)" ::: "memory");
        __builtin_amdgcn_s_barrier();
        if (ks + 2 < 32) {
            int b2 = bk + 2; if (b2 >= 3) b2 -= 3;
            stage(ks + 2, b2);
        }
        bf16x8 a[4], b[4];
        #pragma unroll
        for (int mf = 0; mf < 4; mf++)
            a[mf] = *(bf16x8*)&As[bk][(waveM * 64 + mf * 16 + cl) * 32 + asw];
        #pragma unroll
        for (int nf = 0; nf < 4; nf++)
            b[nf] = *(bf16x8*)&Bs[bk][(waveN * 64 + nf * 16 + cl) * 32 + asw];
        #pragma unroll
        for (int mf = 0; mf < 4; mf++)
            #pragma unroll
            for (int nf = 0; nf < 4; nf++)
                acc[mf][nf] = __builtin_amdgcn_mfma_f32_16x16x32_bf16(a[mf], b[nf], acc[mf][nf], 0, 0, 0);
        bk = (bk == 2) ? 0 : bk + 1;
    }
    #pragma unroll
    for (int mf = 0; mf < 4; mf++)
        #pragma unroll
        for (int nf = 0; nf < 4; nf++)
            #pragma unroll
            for (int r = 0; r < 4; r++) {
                int rg = m0 + waveM * 64 + mf * 16 + 4 * gl + r;
                int cg = n0 + waveN * 64 + nf * 16 + cl;
                out[(size_t)rg * N + cg] = acc[mf][nf][r] + bias[cg];
            }
}

extern "C" void kernel_launch(void* const* d_in, const int* in_sizes, int n_in,
                              void* d_out, int out_size, void* d_ws, size_t ws_size,
                              hipStream_t stream) {
    const float* x      = (const float*)d_in[0];
    const float* w_attn = (const float*)d_in[1];
    const float* b_attn = (const float*)d_in[2];
    const float* w_proj = (const float*)d_in[3];
    const float* b_proj = (const float*)d_in[4];
    float* out = (float*)d_out;

    const size_t E = (size_t)M_ * C_;   // 8388608
    ushort_t* qw  = (ushort_t*)d_ws;
    ushort_t* kw  = qw + E;
    ushort_t* vt  = kw + E;             // [B,H,HS,T]
    ushort_t* xy  = vt + E;             // xb during qkv, then yw [B,T,C]
    ushort_t* wat = xy + E;             // w_attn^T [3072][1024]
    ushort_t* wpt = vt;                 // w_proj^T reuses vt slot after attn

    cvt_x<<<dim3(4096), 256, 0, stream>>>(x, xy);
    transpose_cvt<<<dim3(48, 16), 256, 0, stream>>>(w_attn, wat, C_, 3 * C_);
    qkv_gemm<<<dim3(1536), 256, 0, stream>>>(xy, wat, b_attn, qw, kw, vt);
    attn_mfma<<<dim3(8, 64), 512, 0, stream>>>(qw, kw, vt, xy);
    transpose_cvt<<<dim3(16, 16), 256, 0, stream>>>(w_proj, wpt, C_, C_);
    proj_gemm<<<dim3(512), 256, 0, stream>>>(xy, wpt, b_proj, out);
}